// Round 17
// baseline (123.994 us; speedup 1.0000x reference)
//
#include <hip/hip_runtime.h>
#include <hip/hip_bf16.h>
#include <stdint.h>

#define MB_ 8192
#define FD  512
#define OD  512
#define KD  8704     // F*16 + F (basis + residual)
#define KBASIS 8192
// bt2 tiled geometry: chunk(ct, ks, o) ; ks in [0,1088), o in [0,128), 16B chunks
#define BT_KS   1088
#define BT_CHUNKS_PER_CT (BT_KS * 128)          // 139264
#define BT_BYTES_PER_CT  (BT_CHUNKS_PER_CT * 16) // 2228224
#define TOFF 49152   // t-panel LDS offset (after 3x16KB B bufs)

typedef __attribute__((ext_vector_type(4))) float f32x4;
typedef __attribute__((ext_vector_type(8))) short bf16x8;
typedef __attribute__((ext_vector_type(4))) unsigned int u32x4;
typedef __attribute__((ext_vector_type(2))) unsigned int u32x2;

__device__ __forceinline__ void gload_lds16(const void* g, void* l) {
  __builtin_amdgcn_global_load_lds((const __attribute__((address_space(1))) void*)g,
                                   (__attribute__((address_space(3))) void*)l,
                                   16, 0, 0);
}

__device__ __forceinline__ uint32_t bf_rtn(float f) {
  uint32_t u = __float_as_uint(f);
  return (u + 0x7fffu + ((u >> 16) & 1u)) >> 16;
}

// packed bf16 pair (a in low 16, b in high 16) via HW v_cvt_pk_bf16_f32
__device__ __forceinline__ uint32_t pk(float a, float b) {
  uint32_t r;
  asm("v_cvt_pk_bf16_f32 %0, %1, %2" : "=v"(r) : "v"(a), "v"(b));
  return r;
}

// ---------------- phase 1: t = tanh(x) fp32, xbf = bf16(x) ----------------
__global__ __launch_bounds__(256) void k_tanh(const float* __restrict__ x,
                                              float* __restrict__ t,
                                              uint16_t* __restrict__ xbf) {
  int i = blockIdx.x * 256 + threadIdx.x;   // 0 .. 2^20-1, 4 elems each
  f32x4 v = ((const f32x4*)x)[i];
  f32x4 tv;
  tv[0] = tanhf(v[0]); tv[1] = tanhf(v[1]);
  tv[2] = tanhf(v[2]); tv[3] = tanhf(v[3]);
  ((f32x4*)t)[i] = tv;
  u32x2 p;
  p[0] = pk(v[0], v[1]);
  p[1] = pk(v[2], v[3]);
  ((u32x2*)xbf)[i] = p;
}

// ---------------- phase 2: bt2 tiled repack, SLOT-PERMUTED (PROVEN r12-16) --
// chunk(ct, ks, o): k-slot order per K-step = (f0L,f1L,f2L,f3L,f0H,f1H,f2H,f3H)
// -> A-fragment pair for lane l4 = both halves of ONE feature (one chain/lane).
__global__ __launch_bounds__(256) void k_bt(const float* __restrict__ coeffs,
                                            const float* __restrict__ bw,
                                            uint16_t* __restrict__ bt2,
                                            float* __restrict__ out) {
  int tid = blockIdx.x * 256 + threadIdx.x;  // 0..262143
  {
    int o = tid & 511, i = tid >> 9;         // feature i, out-col o
    const f32x4* src = (const f32x4*)(coeffs + (((size_t)(i * 512 + o)) << 4));
    f32x4 c0 = src[0], c1 = src[1], c2 = src[2], c3 = src[3];
    u32x4 qa, qb;
    qa[0] = pk(c0[0], c0[1]);
    qa[1] = pk(c0[2], c0[3]);
    qa[2] = pk(c1[0], c1[1]);
    qa[3] = pk(c1[2], c1[3]);
    qb[0] = pk(c2[0], c2[1]);
    qb[1] = pk(c2[2], c2[3]);
    qb[2] = pk(c3[0], c3[1]);
    qb[3] = pk(c3[2], c3[3]);
    int slo = ((i >> 2) << 3) | (i & 3);     // lo-half slot of feature i
    size_t cidx = (size_t)(o >> 7) * BT_CHUNKS_PER_CT + (size_t)slo * 128 + (o & 127);
    u32x4* base = (u32x4*)bt2;
    base[cidx]       = qa;   // T0..T7
    base[cidx + 512] = qb;   // T8..T15 (slot + 4)
  }
  {
    int o2 = tid >> 9, i2 = tid & 511;
    size_t cidx = (size_t)(o2 >> 7) * BT_CHUNKS_PER_CT + (size_t)(1024 + (i2 >> 3)) * 128 + (o2 & 127);
    bt2[cidx * 8 + (i2 & 7)] = (uint16_t)bf_rtn(bw[i2 * 512 + o2]);
  }
  if (tid == 0) out[(size_t)MB_ * OD] = 0.0f;   // kl output
}

// ---------------- phase 3: fused GEMM, counted-vmcnt, 2 blocks/CU -----------
// C[8192,512] = A[8192,8704] @ B[8704,512].  Tile 64x128, BK=64.
// ROUND-17: r13's grid-512 / 64x128-tile / 8-wave 2x4 geometry (proven) +
// r15's counted-vmcnt 3-buffer pipeline (proven). 51KB LDS -> 2 blocks/CU
// co-resident = 4 waves/SIMD; cross-block overlap hides the ~700cy/step
// latency that r15 (grid 256 = 1 block/CU) could not mask.
__global__ __launch_bounds__(512, 4) void k_gemm(const float* __restrict__ t,
                                                 const uint16_t* __restrict__ xbf,
                                                 const uint16_t* __restrict__ bt2,
                                                 float* __restrict__ out) {
  __shared__ __align__(128) char lds[52224];  // B 3x16KB | t 3x1KB

  const int tid  = threadIdx.x;       // 0..511
  const int lane = tid & 63;
  const int wid  = tid >> 6;          // 0..7
  const int wr   = wid >> 2;          // 0..1 (row group of 32)
  const int wc   = wid & 3;           // 0..3 (col group of 32)
  const int l15  = lane & 15, l4 = lane >> 4;   // l4 = this lane's feature slot

  // bijective XCD swizzle: 512 blocks, each XCD a contiguous 16-rt band x 4 ct
  int bx  = blockIdx.x;               // 0..511
  int idx = bx >> 3;                  // 0..63
  int rt  = (bx & 7) * 16 + (idx >> 2);  // 0..127
  int ct  = idx & 3;                     // 0..3
  const int brow = rt << 6, bcol = ct << 7;

  const char* btbase = (const char*)bt2 + (size_t)ct * BT_BYTES_PER_CT;
  const int row = brow + wr * 32 + l15;              // m=0 row of this lane
  const uint16_t* x0 = xbf + (size_t)row * FD;
  const uint16_t* x1 = x0 + (size_t)16 * FD;         // m=1 row

  // hoisted LDS base pointers
  const char* bb0 = lds + l4 * 2048 + (wc * 32 + l15) * 16;       // B reads
  const char* tb0 = lds + TOFF + (wr * 32 + l15) * 16 + l4 * 4;   // t reads
  char* sBl = lds + tid * 16;                                     // B stage dst
  char* sTl = lds + TOFF + lane * 16;                             // t stage dst

  const char* sBgBase = btbase + (size_t)tid * 16;
  const char* sTgBase = (const char*)t + (((size_t)(brow + lane)) * FD) * 4;

  f32x4 acc[2][2];
#pragma unroll
  for (int m = 0; m < 2; ++m)
#pragma unroll
    for (int n = 0; n < 2; ++n) acc[m][n] = (f32x4)0.0f;

  u32x4 pf00 = {}, pf01 = {}, pf10 = {}, pf11 = {};   // residual prefetch

  auto stageB = [&](int s2, int b2) {       // 2 loads/thread (16KB total)
    const char* src = sBgBase + ((size_t)s2 << 14);
    gload_lds16(src, sBl + b2 * 16384);
    gload_lds16(src + 8192, sBl + b2 * 16384 + 8192);
  };
  auto stageT = [&](int s2, int b2) {       // 1KB: 64 rows x 4 feats, wave 0
    if (wid == 0)
      gload_lds16(sTgBase + ((size_t)s2 << 4), sTl + b2 * 1024);
  };
  auto chains = [&](const char* tb, u32x4& af00, u32x4& af01,
                    u32x4& af10, u32x4& af11) {
#pragma unroll
    for (int m = 0; m < 2; ++m) {
      float tv = *(const float*)(tb + m * 256);   // feature 4*step + l4, row m
      float c2 = tv + tv;
      float T0 = 1.0f, T1 = tv;
      float T2  = __builtin_fmaf(c2, T1,  -T0);
      float T3  = __builtin_fmaf(c2, T2,  -T1);
      float T4  = __builtin_fmaf(c2, T3,  -T2);
      float T5  = __builtin_fmaf(c2, T4,  -T3);
      float T6  = __builtin_fmaf(c2, T5,  -T4);
      float T7  = __builtin_fmaf(c2, T6,  -T5);
      float T8  = __builtin_fmaf(c2, T7,  -T6);
      float T9  = __builtin_fmaf(c2, T8,  -T7);
      float T10 = __builtin_fmaf(c2, T9,  -T8);
      float T11 = __builtin_fmaf(c2, T10, -T9);
      float T12 = __builtin_fmaf(c2, T11, -T10);
      float T13 = __builtin_fmaf(c2, T12, -T11);
      float T14 = __builtin_fmaf(c2, T13, -T12);
      float T15 = __builtin_fmaf(c2, T14, -T13);
      u32x4 lo, hi;
      lo[0] = pk(T0,  T1);  lo[1] = pk(T2,  T3);
      lo[2] = pk(T4,  T5);  lo[3] = pk(T6,  T7);
      hi[0] = pk(T8,  T9);  hi[1] = pk(T10, T11);
      hi[2] = pk(T12, T13); hi[3] = pk(T14, T15);
      if (m == 0) { af00 = lo; af01 = hi; }
      else        { af10 = lo; af11 = hi; }
    }
  };
  auto mfma8 = [&](const char* bb, const u32x4& af00, const u32x4& af01,
                   const u32x4& af10, const u32x4& af11) {
    bf16x8 a00 = *(const bf16x8*)&af00;   // m=0 h=0
    bf16x8 a01 = *(const bf16x8*)&af01;   // m=0 h=1
    bf16x8 a10 = *(const bf16x8*)&af10;   // m=1 h=0
    bf16x8 a11 = *(const bf16x8*)&af11;   // m=1 h=1
    bf16x8 b00 = *(const bf16x8*)(bb);                 // h=0, n=0
    bf16x8 b01 = *(const bf16x8*)(bb + 256);           // h=0, n=1
    bf16x8 b10 = *(const bf16x8*)(bb + 8192);          // h=1, n=0
    bf16x8 b11 = *(const bf16x8*)(bb + 8192 + 256);    // h=1, n=1
    acc[0][0] = __builtin_amdgcn_mfma_f32_16x16x32_bf16(a00, b00, acc[0][0], 0, 0, 0);
    acc[0][1] = __builtin_amdgcn_mfma_f32_16x16x32_bf16(a00, b01, acc[0][1], 0, 0, 0);
    acc[1][0] = __builtin_amdgcn_mfma_f32_16x16x32_bf16(a10, b00, acc[1][0], 0, 0, 0);
    acc[1][1] = __builtin_amdgcn_mfma_f32_16x16x32_bf16(a10, b01, acc[1][1], 0, 0, 0);
    acc[0][0] = __builtin_amdgcn_mfma_f32_16x16x32_bf16(a01, b10, acc[0][0], 0, 0, 0);
    acc[0][1] = __builtin_amdgcn_mfma_f32_16x16x32_bf16(a01, b11, acc[0][1], 0, 0, 0);
    acc[1][0] = __builtin_amdgcn_mfma_f32_16x16x32_bf16(a11, b10, acc[1][0], 0, 0, 0);
    acc[1][1] = __builtin_amdgcn_mfma_f32_16x16x32_bf16(a11, b11, acc[1][1], 0, 0, 0);
  };
  auto fence_bar = [&]() {   // counted drain: previous batch done, current rides
    if (wid == 0) asm volatile("s_waitcnt vmcnt(3)" ::: "memory");
    else          asm volatile("s_waitcnt vmcnt(2)" ::: "memory");
    __builtin_amdgcn_s_barrier();
    asm volatile("" ::: "memory");
  };

  // prologue: stage steps 0,1 into bufs 0,1; drain batch 0 only
  stageB(0, 0); stageT(0, 0);
  stageB(1, 1); stageT(1, 1);
  fence_bar();

  auto fastbody = [&](int s, int cur, int stg) {   // cur/stg compile-time
    stageB(s + 2, stg);                  // batch(s): step s+2 (basis, s+2<=127)
    stageT(s + 2, stg);
    u32x4 af00, af01, af10, af11;
    chains(tb0 + cur * 1024, af00, af01, af10, af11);
    __builtin_amdgcn_s_setprio(1);
    mfma8(bb0 + cur * 16384, af00, af01, af10, af11);
    __builtin_amdgcn_s_setprio(0);
    fence_bar();
  };

  for (int s = 0; s < 126; s += 3) {     // 42 groups; buf indices compile-time
    fastbody(s,     0, 2);
    fastbody(s + 1, 1, 0);
    fastbody(s + 2, 2, 1);
  }

  // tail: steps 126..135 (basis 126,127 then residual 128..135), full drains
  for (int s = 126; s < 136; ++s) {
    u32x4 af00 = pf00, af01 = pf01, af10 = pf10, af11 = pf11;  // snapshot
    if (s <= 133) stageB(s + 2, (s + 2) % 3);                  // B only
    if (s >= 127 && s <= 134) {          // prefetch xbf for step s+1
      int kres = ((s + 1 - 128) << 6) + l4 * 8;
      pf00 = *(const u32x4*)(x0 + kres);
      pf01 = *(const u32x4*)(x0 + kres + 32);
      pf10 = *(const u32x4*)(x1 + kres);
      pf11 = *(const u32x4*)(x1 + kres + 32);
    }
    if (s < 128)
      chains(tb0 + (s % 3) * 1024, af00, af01, af10, af11);
    mfma8(bb0 + (s % 3) * 16384, af00, af01, af10, af11);
    __syncthreads();                     // full drain (tail only)
  }

  // epilogue: C/D layout col=l&15, row=(l>>4)*4+r  [m89]
#pragma unroll
  for (int m = 0; m < 2; ++m)
#pragma unroll
    for (int n = 0; n < 2; ++n)
#pragma unroll
      for (int r = 0; r < 4; ++r) {
        int grow = brow + wr * 32 + m * 16 + l4 * 4 + r;
        int gcol = bcol + wc * 32 + n * 16 + l15;
        out[(size_t)grow * OD + gcol] = acc[m][n][r];
      }
}

extern "C" void kernel_launch(void* const* d_in, const int* in_sizes, int n_in,
                              void* d_out, int out_size, void* d_ws, size_t ws_size,
                              hipStream_t stream) {
  const float* x      = (const float*)d_in[0];
  const float* coeffs = (const float*)d_in[1];
  const float* bw     = (const float*)d_in[2];
  float* out = (float*)d_out;
  char* ws = (char*)d_ws;

  float*    t   = (float*)ws;                                  // 16 MB fp32 tanh
  uint16_t* xbf = (uint16_t*)(ws + (size_t)16777216);          // 8 MB bf16 x
  uint16_t* bt2 = (uint16_t*)(ws + (size_t)16777216 + 8388608);// 8.5 MB tiled B

  k_tanh<<<4096, 256, 0, stream>>>(x, t, xbf);
  k_bt<<<1024, 256, 0, stream>>>(coeffs, bw, bt2, out);
  k_gemm<<<512, 512, 0, stream>>>(t, xbf, bt2, out);
}

// Round 18
// 104.082 us; speedup vs baseline: 1.1913x; 1.1913x over previous
//
#include <hip/hip_runtime.h>
#include <hip/hip_bf16.h>
#include <stdint.h>

#define MB_ 8192
#define FD  512
#define OD  512
#define KD  8704     // F*16 + F (basis + residual)
#define KBASIS 8192
// bt2 tiled geometry: chunk(ct, ks, o) ; ks in [0,1088), o in [0,128), 16B chunks
#define BT_KS   1088
#define BT_CHUNKS_PER_CT (BT_KS * 128)          // 139264
#define BT_BYTES_PER_CT  (BT_CHUNKS_PER_CT * 16) // 2228224
#define TOFF 98304   // t-panel LDS offset (after 6x16KB B bufs)

typedef __attribute__((ext_vector_type(4))) float f32x4;
typedef __attribute__((ext_vector_type(8))) short bf16x8;
typedef __attribute__((ext_vector_type(4))) unsigned int u32x4;
typedef __attribute__((ext_vector_type(2))) unsigned int u32x2;

__device__ __forceinline__ void gload_lds16(const void* g, void* l) {
  __builtin_amdgcn_global_load_lds((const __attribute__((address_space(1))) void*)g,
                                   (__attribute__((address_space(3))) void*)l,
                                   16, 0, 0);
}

__device__ __forceinline__ uint32_t bf_rtn(float f) {
  uint32_t u = __float_as_uint(f);
  return (u + 0x7fffu + ((u >> 16) & 1u)) >> 16;
}

// packed bf16 pair (a in low 16, b in high 16) via HW v_cvt_pk_bf16_f32
__device__ __forceinline__ uint32_t pk(float a, float b) {
  uint32_t r;
  asm("v_cvt_pk_bf16_f32 %0, %1, %2" : "=v"(r) : "v"(a), "v"(b));
  return r;
}

// ---------------- phase 1: t = tanh(x) fp32, xbf = bf16(x) ----------------
__global__ __launch_bounds__(256) void k_tanh(const float* __restrict__ x,
                                              float* __restrict__ t,
                                              uint16_t* __restrict__ xbf) {
  int i = blockIdx.x * 256 + threadIdx.x;   // 0 .. 2^20-1, 4 elems each
  f32x4 v = ((const f32x4*)x)[i];
  f32x4 tv;
  tv[0] = tanhf(v[0]); tv[1] = tanhf(v[1]);
  tv[2] = tanhf(v[2]); tv[3] = tanhf(v[3]);
  ((f32x4*)t)[i] = tv;
  u32x2 p;
  p[0] = pk(v[0], v[1]);
  p[1] = pk(v[2], v[3]);
  ((u32x2*)xbf)[i] = p;
}

// ---------------- phase 2: bt2 tiled repack, SLOT-PERMUTED (PROVEN r12-17) --
// chunk(ct, ks, o): k-slot order per K-step = (f0L,f1L,f2L,f3L,f0H,f1H,f2H,f3H)
// -> A-fragment pair for lane l4 = both halves of ONE feature (one chain/lane).
__global__ __launch_bounds__(256) void k_bt(const float* __restrict__ coeffs,
                                            const float* __restrict__ bw,
                                            uint16_t* __restrict__ bt2,
                                            float* __restrict__ out) {
  int tid = blockIdx.x * 256 + threadIdx.x;  // 0..262143
  {
    int o = tid & 511, i = tid >> 9;         // feature i, out-col o
    const f32x4* src = (const f32x4*)(coeffs + (((size_t)(i * 512 + o)) << 4));
    f32x4 c0 = src[0], c1 = src[1], c2 = src[2], c3 = src[3];
    u32x4 qa, qb;
    qa[0] = pk(c0[0], c0[1]);
    qa[1] = pk(c0[2], c0[3]);
    qa[2] = pk(c1[0], c1[1]);
    qa[3] = pk(c1[2], c1[3]);
    qb[0] = pk(c2[0], c2[1]);
    qb[1] = pk(c2[2], c2[3]);
    qb[2] = pk(c3[0], c3[1]);
    qb[3] = pk(c3[2], c3[3]);
    int slo = ((i >> 2) << 3) | (i & 3);     // lo-half slot of feature i
    size_t cidx = (size_t)(o >> 7) * BT_CHUNKS_PER_CT + (size_t)slo * 128 + (o & 127);
    u32x4* base = (u32x4*)bt2;
    base[cidx]       = qa;   // T0..T7
    base[cidx + 512] = qb;   // T8..T15 (slot + 4)
  }
  {
    int o2 = tid >> 9, i2 = tid & 511;
    size_t cidx = (size_t)(o2 >> 7) * BT_CHUNKS_PER_CT + (size_t)(1024 + (i2 >> 3)) * 128 + (o2 & 127);
    bt2[cidx * 8 + (i2 & 7)] = (uint16_t)bf_rtn(bw[i2 * 512 + o2]);
  }
  if (tid == 0) out[(size_t)MB_ * OD] = 0.0f;   // kl output
}

// ---------------- phase 3: fused GEMM, paired counted-vmcnt pipeline --------
// C[8192,512] = A[8192,8704] @ B[8704,512].  Tile 128x128, BK=64, 8 waves 4x2.
// ROUND-18: r15 (101.7us, best) with fences HALVED — 6 LDS buffers, process
// K-steps in PAIRS, one counted fence per pair (vmcnt(4); t-waves vmcnt(6) =
// exactly the just-issued pair-batch stays in flight). Buffer reuse distance
// 6 steps = 3 fences -> race-safe. Data paths byte-identical to r15.
__global__ __launch_bounds__(512, 2) void k_gemm(const float* __restrict__ t,
                                                 const uint16_t* __restrict__ xbf,
                                                 const uint16_t* __restrict__ bt2,
                                                 float* __restrict__ out) {
  __shared__ __align__(128) char lds[110592];  // B 6x16KB | t 6x2KB

  const int tid  = threadIdx.x;       // 0..511
  const int lane = tid & 63;
  const int wid  = tid >> 6;          // 0..7
  const int wr   = wid >> 1;          // 0..3 (row group of 32)
  const int wc   = wid & 1;           // 0..1 (col group of 64)
  const int l15  = lane & 15, l4 = lane >> 4;   // l4 = this lane's feature slot

  // bijective XCD swizzle: each XCD gets 8 row-tiles x 4 col-tiles
  int bx  = blockIdx.x;               // 0..255
  int idx = bx >> 3;
  int rt  = (bx & 7) * 8 + (idx >> 2);   // 0..63
  int ct  = idx & 3;                     // 0..3
  const int brow = rt << 7, bcol = ct << 7;

  const char* btbase = (const char*)bt2 + (size_t)ct * BT_BYTES_PER_CT;
  const int row = brow + wr * 32 + l15;              // m=0 row of this lane
  const uint16_t* x0 = xbf + (size_t)row * FD;
  const uint16_t* x1 = x0 + (size_t)16 * FD;         // m=1 row

  // hoisted LDS base pointers
  const char* bb0 = lds + l4 * 2048 + (wc * 64 + l15) * 16;       // B reads
  const char* tb0 = lds + TOFF + (wr * 32 + l15) * 16 + l4 * 4;   // t reads
  char* sBl = lds + tid * 16;                                     // B stage dst
  char* sTl = lds + TOFF + wid * 1024 + lane * 16;                // t stage dst

  const char* sBgBase = btbase + (size_t)tid * 16;
  const char* sTgBase = (const char*)t + (((size_t)(brow + wid * 64 + lane)) * FD) * 4;

  f32x4 acc[2][4];
#pragma unroll
  for (int m = 0; m < 2; ++m)
#pragma unroll
    for (int n = 0; n < 4; ++n) acc[m][n] = (f32x4)0.0f;

  u32x4 pf00 = {}, pf01 = {}, pf10 = {}, pf11 = {};   // residual prefetch

  auto stageB = [&](int s2, int b2) {       // 2 loads/thread (16KB panel)
    const char* src = sBgBase + ((size_t)s2 << 14);
    gload_lds16(src, sBl + b2 * 16384);
    gload_lds16(src + 8192, sBl + b2 * 16384 + 8192);
  };
  auto stageT = [&](int s2, int b2) {       // stage t for basis step s2
    if (wid < 2)
      gload_lds16(sTgBase + ((size_t)s2 << 4), sTl + b2 * 2048);
  };
  auto chains = [&](const char* tb, u32x4& af00, u32x4& af01,
                    u32x4& af10, u32x4& af11) {
#pragma unroll
    for (int m = 0; m < 2; ++m) {
      float tv = *(const float*)(tb + m * 256);   // feature 4*step + l4, row m
      float c2 = tv + tv;
      float T0 = 1.0f, T1 = tv;
      float T2  = __builtin_fmaf(c2, T1,  -T0);
      float T3  = __builtin_fmaf(c2, T2,  -T1);
      float T4  = __builtin_fmaf(c2, T3,  -T2);
      float T5  = __builtin_fmaf(c2, T4,  -T3);
      float T6  = __builtin_fmaf(c2, T5,  -T4);
      float T7  = __builtin_fmaf(c2, T6,  -T5);
      float T8  = __builtin_fmaf(c2, T7,  -T6);
      float T9  = __builtin_fmaf(c2, T8,  -T7);
      float T10 = __builtin_fmaf(c2, T9,  -T8);
      float T11 = __builtin_fmaf(c2, T10, -T9);
      float T12 = __builtin_fmaf(c2, T11, -T10);
      float T13 = __builtin_fmaf(c2, T12, -T11);
      float T14 = __builtin_fmaf(c2, T13, -T12);
      float T15 = __builtin_fmaf(c2, T14, -T13);
      u32x4 lo, hi;
      lo[0] = pk(T0,  T1);  lo[1] = pk(T2,  T3);
      lo[2] = pk(T4,  T5);  lo[3] = pk(T6,  T7);
      hi[0] = pk(T8,  T9);  hi[1] = pk(T10, T11);
      hi[2] = pk(T12, T13); hi[3] = pk(T14, T15);
      if (m == 0) { af00 = lo; af01 = hi; }
      else        { af10 = lo; af11 = hi; }
    }
  };
  auto mfma16 = [&](const char* bb, const u32x4& af00, const u32x4& af01,
                    const u32x4& af10, const u32x4& af11) {
    bf16x8 a00 = *(const bf16x8*)&af00;
    bf16x8 a01 = *(const bf16x8*)&af01;
    bf16x8 a10 = *(const bf16x8*)&af10;
    bf16x8 a11 = *(const bf16x8*)&af11;
#pragma unroll
    for (int n = 0; n < 4; ++n) {
      bf16x8 b0 = *(const bf16x8*)(bb + n * 256);          // h=0
      bf16x8 b1 = *(const bf16x8*)(bb + 8192 + n * 256);   // h=1
      acc[0][n] = __builtin_amdgcn_mfma_f32_16x16x32_bf16(a00, b0, acc[0][n], 0, 0, 0);
      acc[1][n] = __builtin_amdgcn_mfma_f32_16x16x32_bf16(a10, b0, acc[1][n], 0, 0, 0);
      acc[0][n] = __builtin_amdgcn_mfma_f32_16x16x32_bf16(a01, b1, acc[0][n], 0, 0, 0);
      acc[1][n] = __builtin_amdgcn_mfma_f32_16x16x32_bf16(a11, b1, acc[1][n], 0, 0, 0);
    }
  };
  auto fence_bar = [&]() {   // counted drain: only the just-issued pair rides
    if (wid < 2) asm volatile("s_waitcnt vmcnt(6)" ::: "memory");
    else         asm volatile("s_waitcnt vmcnt(4)" ::: "memory");
    __builtin_amdgcn_s_barrier();
    asm volatile("" ::: "memory");
  };

  // prologue: stage step-pairs (0,1) and (2,3); drain pair(0,1), leave (2,3)
  stageB(0, 0); stageT(0, 0);
  stageB(1, 1); stageT(1, 1);
  stageB(2, 2); stageT(2, 2);
  stageB(3, 3); stageT(3, 3);
  fence_bar();

  // pair body: consume steps s,s+1 (bufs c0,c1); stage s+4,s+5 (bufs g0,g1)
  auto pairbody = [&](int s, int c0, int c1, int g0, int g1) {
    stageB(s + 4, g0); stageT(s + 4, g0);
    stageB(s + 5, g1); stageT(s + 5, g1);
    u32x4 af00, af01, af10, af11;
    chains(tb0 + c0 * 2048, af00, af01, af10, af11);
    __builtin_amdgcn_s_setprio(1);
    mfma16(bb0 + c0 * 16384, af00, af01, af10, af11);
    __builtin_amdgcn_s_setprio(0);
    chains(tb0 + c1 * 2048, af00, af01, af10, af11);
    __builtin_amdgcn_s_setprio(1);
    mfma16(bb0 + c1 * 16384, af00, af01, af10, af11);
    __builtin_amdgcn_s_setprio(0);
    fence_bar();
  };

  // fast region: steps 0..123 (62 pair-iters; buf pattern period 3)
  for (int s = 0; s < 120; s += 6) {
    pairbody(s,     0, 1, 4, 5);
    pairbody(s + 2, 2, 3, 0, 1);
    pairbody(s + 4, 4, 5, 2, 3);
  }
  pairbody(120, 0, 1, 4, 5);      // stages 124,125 -> bufs 4,5
  pairbody(122, 2, 3, 0, 1);      // stages 126,127 -> bufs 0,1

  // tail: steps 124..135 (basis 124..127 then residual 128..135), full drains
  for (int s = 124; s < 136; ++s) {
    u32x4 af00 = pf00, af01 = pf01, af10 = pf10, af11 = pf11;  // snapshot
    if (s >= 126 && s <= 133) stageB(s + 2, (s + 2) % 6);      // B-only
    if (s >= 127 && s <= 134) {          // prefetch xbf for step s+1
      int kres = ((s + 1 - 128) << 6) + l4 * 8;
      pf00 = *(const u32x4*)(x0 + kres);
      pf01 = *(const u32x4*)(x0 + kres + 32);
      pf10 = *(const u32x4*)(x1 + kres);
      pf11 = *(const u32x4*)(x1 + kres + 32);
    }
    if (s < 128)
      chains(tb0 + (s % 6) * 2048, af00, af01, af10, af11);
    mfma16(bb0 + (s % 6) * 16384, af00, af01, af10, af11);
    __syncthreads();                     // full drain (tail only)
  }

  // epilogue: C/D layout col=l&15, row=(l>>4)*4+r  [m89]
#pragma unroll
  for (int m = 0; m < 2; ++m)
#pragma unroll
    for (int n = 0; n < 4; ++n)
#pragma unroll
      for (int r = 0; r < 4; ++r) {
        int grow = brow + wr * 32 + m * 16 + l4 * 4 + r;
        int gcol = bcol + wc * 64 + n * 16 + l15;
        out[(size_t)grow * OD + gcol] = acc[m][n][r];
      }
}

extern "C" void kernel_launch(void* const* d_in, const int* in_sizes, int n_in,
                              void* d_out, int out_size, void* d_ws, size_t ws_size,
                              hipStream_t stream) {
  const float* x      = (const float*)d_in[0];
  const float* coeffs = (const float*)d_in[1];
  const float* bw     = (const float*)d_in[2];
  float* out = (float*)d_out;
  char* ws = (char*)d_ws;

  float*    t   = (float*)ws;                                  // 16 MB fp32 tanh
  uint16_t* xbf = (uint16_t*)(ws + (size_t)16777216);          // 8 MB bf16 x
  uint16_t* bt2 = (uint16_t*)(ws + (size_t)16777216 + 8388608);// 8.5 MB tiled B

  k_tanh<<<4096, 256, 0, stream>>>(x, t, xbf);
  k_bt<<<1024, 256, 0, stream>>>(coeffs, bw, bt2, out);
  k_gemm<<<256, 512, 0, stream>>>(t, xbf, bt2, out);
}